// Round 7
// baseline (139.623 us; speedup 1.0000x reference)
//
#include <hip/hip_runtime.h>
#include <hip/hip_bf16.h>
#include <math.h>

typedef __bf16 bf16x8 __attribute__((ext_vector_type(8)));
typedef float f32x4 __attribute__((ext_vector_type(4)));
typedef unsigned short u16x8 __attribute__((ext_vector_type(8)));
typedef unsigned short u16;

#define S_LEN 2048
#define DMODEL 1024
#define NH 16

__device__ __forceinline__ u16 f2bf(float f) {
    __bf16 b = (__bf16)f;
    return __builtin_bit_cast(u16, b);
}
__device__ __forceinline__ float bf2f(u16 u) {
    union { unsigned int i; float f; } v; v.i = ((unsigned int)u) << 16; return v.f;
}

// global -> LDS direct copy, 16B per lane. lds dest is the WAVE-UNIFORM base
// (hardware adds lane*16); global src is per-lane (pre-swizzled for XOR layouts).
__device__ __forceinline__ void gload16(const u16* g, u16* lds_base) {
    __builtin_amdgcn_global_load_lds(
        (const __attribute__((address_space(1))) unsigned int*)g,
        (__attribute__((address_space(3))) unsigned int*)lds_base,
        16, 0, 0);
}

// ---------- X f32 -> bf16 ----------
__global__ __launch_bounds__(256) void cvt_x(const float* __restrict__ in, u16* __restrict__ outp) {
    int i = (blockIdx.x * 256 + threadIdx.x) * 4;
    float4 v = *(const float4*)(in + i);
    outp[i + 0] = f2bf(v.x); outp[i + 1] = f2bf(v.y);
    outp[i + 2] = f2bf(v.z); outp[i + 3] = f2bf(v.w);
}

// ---------- W [1024][3072] f32 -> Wt [3072][1024] bf16 ----------
__global__ __launch_bounds__(256) void transpose_w(const float* __restrict__ W, u16* __restrict__ Wt) {
    __shared__ u16 tile[32][33];
    int n0 = blockIdx.x * 32, k0 = blockIdx.y * 32;
    int tx = threadIdx.x & 31, ty = threadIdx.x >> 5;
#pragma unroll
    for (int i = 0; i < 4; i++) {
        int k = ty + i * 8;
        tile[k][tx] = f2bf(W[(size_t)(k0 + k) * 3072 + n0 + tx]);
    }
    __syncthreads();
#pragma unroll
    for (int i = 0; i < 4; i++) {
        int n = ty + i * 8;
        Wt[(size_t)(n0 + n) * 1024 + k0 + tx] = tile[tx][n];
    }
}

// ---------- QKV GEMM: global_load_lds staging (m97 pattern), pre-swizzled source ----------
__global__ __launch_bounds__(256) void qkv_gemm(const u16* __restrict__ A, const u16* __restrict__ Bt,
                                                u16* __restrict__ C) {
    __shared__ alignas(16) u16 As[128 * 64];
    __shared__ alignas(16) u16 Bs[128 * 64];
    const int tid = threadIdx.x, l = tid & 63, w = tid >> 6;
    const int bm = blockIdx.y, bn = blockIdx.x;
    const int wm = w >> 1, wn = w & 1;
    const int c0 = l & 15, g = l >> 4;
    f32x4 acc[4][4] = {};
    for (int kt = 0; kt < 1024; kt += 64) {
        __syncthreads();
#pragma unroll
        for (int n = 0; n < 4; n++) {
            int i = tid + n * 256;
            int r = i >> 3, c = i & 7;
            int cs = c ^ (r & 7);
            u16* dstA = As + (size_t)(w * 64 + n * 256) * 8;   // wave-uniform
            u16* dstB = Bs + (size_t)(w * 64 + n * 256) * 8;
            gload16(A + (size_t)(bm * 128 + r) * 1024 + kt + cs * 8, dstA);
            gload16(Bt + (size_t)(bn * 128 + r) * 1024 + kt + cs * 8, dstB);
        }
        __syncthreads();
#pragma unroll
        for (int kk = 0; kk < 2; kk++) {
            bf16x8 af[4], bfr[4];
#pragma unroll
            for (int m = 0; m < 4; m++) {
                int row = wm * 64 + m * 16 + c0;
                af[m] = *(const bf16x8*)((const char*)As + row * 128 + (((g + kk * 4) ^ (row & 7)) << 4));
            }
#pragma unroll
            for (int n = 0; n < 4; n++) {
                int row = wn * 64 + n * 16 + c0;
                bfr[n] = *(const bf16x8*)((const char*)Bs + row * 128 + (((g + kk * 4) ^ (row & 7)) << 4));
            }
#pragma unroll
            for (int m = 0; m < 4; m++)
#pragma unroll
                for (int n = 0; n < 4; n++)
                    acc[m][n] = __builtin_amdgcn_mfma_f32_16x16x32_bf16(af[m], bfr[n], acc[m][n], 0, 0, 0);
        }
    }
#pragma unroll
    for (int m = 0; m < 4; m++)
#pragma unroll
        for (int n = 0; n < 4; n++)
#pragma unroll
            for (int j = 0; j < 4; j++) {
                int row = bm * 128 + wm * 64 + m * 16 + 4 * g + j;
                int col = bn * 128 + wn * 64 + n * 16 + c0;
                C[(size_t)row * 3072 + col] = f2bf(acc[m][n][j]);
            }
}

// ---------- V -> permuted V^T: Vtp[bh][d][spos], spos = (s&~63) | perm(s&63) ----------
__global__ __launch_bounds__(256) void transpose_v(const u16* __restrict__ QKV, u16* __restrict__ Vtp) {
    __shared__ u16 tile[64][72];
    const int bh = blockIdx.x >> 5, st = blockIdx.x & 31;
    const int b = bh >> 4, h = bh & 15;
    const u16* src = QKV + (size_t)b * S_LEN * 3072 + 2048 + h * 64;
    const int sl = threadIdx.x >> 2;
    const int cg = (threadIdx.x & 3) * 16;
#pragma unroll
    for (int ii = 0; ii < 2; ii++) {
        u16x8 v = *(const u16x8*)(src + (size_t)(st * 64 + sl) * 3072 + cg + ii * 8);
        *(u16x8*)&tile[sl][cg + ii * 8] = v;
    }
    __syncthreads();
    const int dl = threadIdx.x >> 2;
#pragma unroll
    for (int ii = 0; ii < 2; ii++) {
        u16x8 o;
#pragma unroll
        for (int q = 0; q < 8; q++) {
            int p = cg + ii * 8 + q;
            int kb = 2 * (p >> 5) + ((p >> 2) & 1);
            int t = kb * 16 + ((p >> 3) & 3) * 4 + (p & 3);
            o[q] = tile[t][dl];
        }
        *(u16x8*)(Vtp + ((size_t)bh * 64 + dl) * S_LEN + st * 64 + cg + ii * 8) = o;
    }
}

// ---------- Flash attention v7: attn4 shape (4 waves x 16 q, 64-slot phases, 32 phases)
// with TWO independent 32-key streams per phase from opposite KV halves (in-wave KV-split).
// K slots 0-31 <- half0 keys, 32-63 <- half1. V pos-cols likewise (Vtp perm maps 0-31->0-31).
// Two independent softmax chains (2-way ILP); in-wave merge at end. ----------
__global__ __launch_bounds__(256) void attn7(const u16* __restrict__ QKV, const u16* __restrict__ Vtp,
                                             float* __restrict__ outp) {
    __shared__ alignas(16) u16 Ks[2][64 * 64];   // [slot][d] chunks, chunk^=(slot&7)
    __shared__ alignas(16) u16 Vs[2][64 * 64];   // [d][pos] chunks, chunk^=(d&7)
    const int bid = blockIdx.x;
    const int wg = ((bid & 7) << 7) | (bid >> 3);   // XCD-chunked swizzle (bijective: 1024=8*128)
    const int tid = threadIdx.x, l = tid & 63, w = tid >> 6;
    const int qt = wg & 31, bh = wg >> 5;
    const int b = bh >> 4, h = bh & 15;
    const int c0 = l & 15, g = l >> 4;
    const u16* Qb = QKV + (size_t)b * S_LEN * 3072 + h * 64;
    const u16* Kb = Qb + 1024;
    const u16* Vb = Vtp + (size_t)bh * 64 * S_LEN;
    const int qrow = qt * 64 + w * 16 + c0;

    // staging: chunk i0=tid (LDS rows 0-31), i1=tid+256 (rows 32-63); swizzled source col
    const int r0 = tid >> 3, cs0 = (tid & 7) ^ (r0 & 7);
    const int i1 = tid + 256;
    const int r1 = i1 >> 3, cs1 = (i1 & 7) ^ (r1 & 7);
    // K: slot r<32 -> global key t*32 + r (half0); slot r>=32 -> t*32 + 1024 + (r-32)
    const int krow0 = r0;                       // r0 in [0,32)
    const int krow1 = 1024 + (r1 - 32);         // r1 in [32,64)
    // V: chunk c' covers pos c'*8..+7; c'<4 -> half0 col t*32 + c'*8; c'>=4 -> half1
    const int vcol0 = (cs0 & 3) * 8 + (cs0 >> 2) * 1024;
    const int vcol1 = (cs1 & 3) * 8 + (cs1 >> 2) * 1024;
    const int dbA = (w * 64) * 8, dbB = (256 + w * 64) * 8;   // wave-uniform LDS dests

    // unified LDS read offsets: koff[x*2+kk] serves K-frag (x=kb) AND V-frag (x=n),
    // since (key&7)==(d&7)==(c0&7) independent of the *16 block index.
    int koff[8];
#pragma unroll
    for (int x = 0; x < 4; x++)
#pragma unroll
        for (int kk = 0; kk < 2; kk++)
            koff[x * 2 + kk] = (x * 16 + c0) * 128 + (((g + kk * 4) ^ (c0 & 7)) << 4);

    // Q B-frags; fold (1/8)*log2(e)
    bf16x8 qf[2];
    {
        const float qs = 0.125f * 1.44269504f;
#pragma unroll
        for (int kk = 0; kk < 2; kk++) {
            u16x8 v = *(const u16x8*)(Qb + (size_t)qrow * 3072 + kk * 32 + g * 8);
            bf16x8 q;
#pragma unroll
            for (int j = 0; j < 8; j++) q[j] = (__bf16)(bf2f(v[j]) * qs);
            qf[kk] = q;
        }
    }
    bf16x8 vone;
#pragma unroll
    for (int j = 0; j < 8; j++) vone[j] = (__bf16)1.0f;

    float m_a = -INFINITY, m_b = -INFINITY;
    f32x4 accOa[4] = {}, accOb[4] = {};
    f32x4 accLa = {}, accLb = {};

    // prologue: stage phase 0 into buf 0
    gload16(Kb + (size_t)krow0 * 3072 + cs0 * 8, Ks[0] + dbA);
    gload16(Kb + (size_t)krow1 * 3072 + cs1 * 8, Ks[0] + dbB);
    gload16(Vb + (size_t)r0 * S_LEN + vcol0, Vs[0] + dbA);
    gload16(Vb + (size_t)r1 * S_LEN + vcol1, Vs[0] + dbB);

    for (int t = 0; t < 32; t++) {
        const int cur = t & 1;
        __syncthreads();  // buf[cur] staged (vmcnt drained at barrier) + prev reads done
        if (t + 1 < 32) {
            const int s0 = (t + 1) * 32;
            gload16(Kb + (size_t)(s0 + krow0) * 3072 + cs0 * 8, Ks[cur ^ 1] + dbA);
            gload16(Kb + (size_t)(s0 + krow1) * 3072 + cs1 * 8, Ks[cur ^ 1] + dbB);
            gload16(Vb + (size_t)r0 * S_LEN + s0 + vcol0, Vs[cur ^ 1] + dbA);
            gload16(Vb + (size_t)r1 * S_LEN + s0 + vcol1, Vs[cur ^ 1] + dbB);
        }
        const char* Kc = (const char*)Ks[cur];
        const char* Vc = (const char*)Vs[cur];
        // QK^T (swapped): sc[kb] rows = slot 16kb+4g+j, col c0 = q. kb 0-1 = stream A, 2-3 = B.
        f32x4 sc[4] = {};
        __builtin_amdgcn_s_setprio(1);
#pragma unroll
        for (int kb = 0; kb < 4; kb++)
#pragma unroll
            for (int kk = 0; kk < 2; kk++) {
                bf16x8 kf = *(const bf16x8*)(Kc + koff[kb * 2 + kk]);
                sc[kb] = __builtin_amdgcn_mfma_f32_16x16x32_bf16(kf, qf[kk], sc[kb], 0, 0, 0);
            }
        __builtin_amdgcn_s_setprio(0);
        // V fragment reads (vf[kk][n]; kk=0 -> pos 0-31 = stream A, kk=1 -> stream B)
        bf16x8 vf[2][4];
#pragma unroll
        for (int kk = 0; kk < 2; kk++)
#pragma unroll
            for (int n = 0; n < 4; n++)
                vf[kk][n] = *(const bf16x8*)(Vc + koff[n * 2 + kk]);
        // --- softmax stream A (sc[0],sc[1]) — independent of stream B: 2-way ILP ---
        float mxA = fmaxf(fmaxf(fmaxf(sc[0][0], sc[0][1]), fmaxf(sc[0][2], sc[0][3])),
                          fmaxf(fmaxf(sc[1][0], sc[1][1]), fmaxf(sc[1][2], sc[1][3])));
        mxA = fmaxf(mxA, __shfl_xor(mxA, 16));
        mxA = fmaxf(mxA, __shfl_xor(mxA, 32));
        float mxB = fmaxf(fmaxf(fmaxf(sc[2][0], sc[2][1]), fmaxf(sc[2][2], sc[2][3])),
                          fmaxf(fmaxf(sc[3][0], sc[3][1]), fmaxf(sc[3][2], sc[3][3])));
        mxB = fmaxf(mxB, __shfl_xor(mxB, 16));
        mxB = fmaxf(mxB, __shfl_xor(mxB, 32));
        // defer-max (T13) per stream
        if (!__all(mxA <= m_a + 8.f)) {
            float mnew = fmaxf(m_a, mxA);
            float alpha = __builtin_amdgcn_exp2f(m_a - mnew);
            m_a = mnew;
#pragma unroll
            for (int j = 0; j < 4; j++) {
                float aj = __shfl(alpha, 20 * g + j);
                accLa[j] *= aj;
#pragma unroll
                for (int n = 0; n < 4; n++) accOa[n][j] *= aj;
            }
        }
        if (!__all(mxB <= m_b + 8.f)) {
            float mnew = fmaxf(m_b, mxB);
            float alpha = __builtin_amdgcn_exp2f(m_b - mnew);
            m_b = mnew;
#pragma unroll
            for (int j = 0; j < 4; j++) {
                float aj = __shfl(alpha, 20 * g + j);
                accLb[j] *= aj;
#pragma unroll
                for (int n = 0; n < 4; n++) accOb[n][j] *= aj;
            }
        }
#pragma unroll
        for (int kb = 0; kb < 2; kb++)
#pragma unroll
            for (int j = 0; j < 4; j++) {
                sc[kb][j]     = __builtin_amdgcn_exp2f(sc[kb][j] - m_a);
                sc[kb + 2][j] = __builtin_amdgcn_exp2f(sc[kb + 2][j] - m_b);
            }
        // --- PV per stream (pf lane-local; A uses vf[0], B uses vf[1]) ---
        __builtin_amdgcn_s_setprio(1);
        {
            bf16x8 pfa, pfb;
#pragma unroll
            for (int j = 0; j < 4; j++) {
                pfa[j] = (__bf16)sc[0][j]; pfa[j + 4] = (__bf16)sc[1][j];
                pfb[j] = (__bf16)sc[2][j]; pfb[j + 4] = (__bf16)sc[3][j];
            }
            accLa = __builtin_amdgcn_mfma_f32_16x16x32_bf16(pfa, vone, accLa, 0, 0, 0);
            accLb = __builtin_amdgcn_mfma_f32_16x16x32_bf16(pfb, vone, accLb, 0, 0, 0);
#pragma unroll
            for (int n = 0; n < 4; n++) {
                accOa[n] = __builtin_amdgcn_mfma_f32_16x16x32_bf16(pfa, vf[0][n], accOa[n], 0, 0, 0);
                accOb[n] = __builtin_amdgcn_mfma_f32_16x16x32_bf16(pfb, vf[1][n], accOb[n], 0, 0, 0);
            }
        }
        __builtin_amdgcn_s_setprio(0);
    }
    // in-wave merge of the two halves + epilogue (row j = q 4g+j, col c0 = d)
    float mM = fmaxf(m_a, m_b);
    float wA = __builtin_amdgcn_exp2f(m_a - mM);
    float wB = __builtin_amdgcn_exp2f(m_b - mM);
#pragma unroll
    for (int j = 0; j < 4; j++) {
        float ajA = __shfl(wA, 20 * g + j);
        float ajB = __shfl(wB, 20 * g + j);
        float inv = 1.0f / (accLa[j] * ajA + accLb[j] * ajB);
        int row = qt * 64 + w * 16 + 4 * g + j;
        float* op = outp + ((size_t)b * S_LEN + row) * DMODEL + h * 64;
#pragma unroll
        for (int n = 0; n < 4; n++)
            op[n * 16 + c0] = (accOa[n][j] * ajA + accOb[n][j] * ajB) * inv;
    }
}

extern "C" void kernel_launch(void* const* d_in, const int* in_sizes, int n_in,
                              void* d_out, int out_size, void* d_ws, size_t ws_size,
                              hipStream_t stream) {
    const float* X = (const float*)d_in[0];
    const float* W = (const float*)d_in[1];
    float* out = (float*)d_out;

    u16* Xb  = (u16*)d_ws;                        // 4096*1024 bf16
    u16* Wt  = Xb + (size_t)4096 * 1024;          // 3072*1024 bf16
    u16* QKV = Wt + (size_t)3072 * 1024;          // 4096*3072 bf16
    u16* Vtp = QKV + (size_t)4096 * 3072;         // 32*64*2048 bf16 (~48MB total)

    cvt_x<<<4096, 256, 0, stream>>>(X, Xb);
    transpose_w<<<dim3(96, 32), 256, 0, stream>>>(W, Wt);
    qkv_gemm<<<dim3(24, 32), 256, 0, stream>>>(Xb, Wt, QKV);
    transpose_v<<<1024, 256, 0, stream>>>(QKV, Vtp);
    attn7<<<1024, 256, 0, stream>>>(QKV, Vtp, out);
}

// Round 8
// 116.706 us; speedup vs baseline: 1.1964x; 1.1964x over previous
//
#include <hip/hip_runtime.h>
#include <hip/hip_bf16.h>
#include <math.h>

typedef __bf16 bf16x8 __attribute__((ext_vector_type(8)));
typedef float f32x4 __attribute__((ext_vector_type(4)));
typedef float f32x16 __attribute__((ext_vector_type(16)));
typedef unsigned short u16x8 __attribute__((ext_vector_type(8)));
typedef unsigned int u32x4 __attribute__((ext_vector_type(4)));
typedef unsigned short u16;

#define S_LEN 2048
#define DMODEL 1024
#define NH 16

__device__ __forceinline__ u16 f2bf(float f) {
    __bf16 b = (__bf16)f;
    return __builtin_bit_cast(u16, b);
}
__device__ __forceinline__ float bf2f(u16 u) {
    union { unsigned int i; float f; } v; v.i = ((unsigned int)u) << 16; return v.f;
}
__device__ __forceinline__ unsigned int pk2(float a, float b) {
    return (unsigned int)f2bf(a) | ((unsigned int)f2bf(b) << 16);
}

// global -> LDS direct copy, 16B per lane (lane-uniform LDS base + lane*16).
__device__ __forceinline__ void gload16(const u16* g, u16* lds_base) {
    __builtin_amdgcn_global_load_lds(
        (const __attribute__((address_space(1))) unsigned int*)g,
        (__attribute__((address_space(3))) unsigned int*)lds_base,
        16, 0, 0);
}

// ---------- X f32 -> bf16 ----------
__global__ __launch_bounds__(256) void cvt_x(const float* __restrict__ in, u16* __restrict__ outp) {
    int i = (blockIdx.x * 256 + threadIdx.x) * 4;
    float4 v = *(const float4*)(in + i);
    outp[i + 0] = f2bf(v.x); outp[i + 1] = f2bf(v.y);
    outp[i + 2] = f2bf(v.z); outp[i + 3] = f2bf(v.w);
}

// ---------- W [1024][3072] f32 -> Wt [3072][1024] bf16 ----------
__global__ __launch_bounds__(256) void transpose_w(const float* __restrict__ W, u16* __restrict__ Wt) {
    __shared__ u16 tile[32][33];
    int n0 = blockIdx.x * 32, k0 = blockIdx.y * 32;
    int tx = threadIdx.x & 31, ty = threadIdx.x >> 5;
#pragma unroll
    for (int i = 0; i < 4; i++) {
        int k = ty + i * 8;
        tile[k][tx] = f2bf(W[(size_t)(k0 + k) * 3072 + n0 + tx]);
    }
    __syncthreads();
#pragma unroll
    for (int i = 0; i < 4; i++) {
        int n = ty + i * 8;
        Wt[(size_t)(n0 + n) * 1024 + k0 + tx] = tile[tx][n];
    }
}

// ---------- QKV GEMM (unchanged, ~860 TF) ----------
__global__ __launch_bounds__(256) void qkv_gemm(const u16* __restrict__ A, const u16* __restrict__ Bt,
                                                u16* __restrict__ C) {
    __shared__ alignas(16) u16 As[128 * 64];
    __shared__ alignas(16) u16 Bs[128 * 64];
    const int tid = threadIdx.x, l = tid & 63, w = tid >> 6;
    const int bm = blockIdx.y, bn = blockIdx.x;
    const int wm = w >> 1, wn = w & 1;
    const int c0 = l & 15, g = l >> 4;
    f32x4 acc[4][4] = {};
    for (int kt = 0; kt < 1024; kt += 64) {
        __syncthreads();
#pragma unroll
        for (int n = 0; n < 4; n++) {
            int i = tid + n * 256;
            int r = i >> 3, c = i & 7;
            int cs = c ^ (r & 7);
            u16* dstA = As + (size_t)(w * 64 + n * 256) * 8;
            u16* dstB = Bs + (size_t)(w * 64 + n * 256) * 8;
            gload16(A + (size_t)(bm * 128 + r) * 1024 + kt + cs * 8, dstA);
            gload16(Bt + (size_t)(bn * 128 + r) * 1024 + kt + cs * 8, dstB);
        }
        __syncthreads();
#pragma unroll
        for (int kk = 0; kk < 2; kk++) {
            bf16x8 af[4], bfr[4];
#pragma unroll
            for (int m = 0; m < 4; m++) {
                int row = wm * 64 + m * 16 + c0;
                af[m] = *(const bf16x8*)((const char*)As + row * 128 + (((g + kk * 4) ^ (row & 7)) << 4));
            }
#pragma unroll
            for (int n = 0; n < 4; n++) {
                int row = wn * 64 + n * 16 + c0;
                bfr[n] = *(const bf16x8*)((const char*)Bs + row * 128 + (((g + kk * 4) ^ (row & 7)) << 4));
            }
#pragma unroll
            for (int m = 0; m < 4; m++)
#pragma unroll
                for (int n = 0; n < 4; n++)
                    acc[m][n] = __builtin_amdgcn_mfma_f32_16x16x32_bf16(af[m], bfr[n], acc[m][n], 0, 0, 0);
        }
    }
#pragma unroll
    for (int m = 0; m < 4; m++)
#pragma unroll
        for (int n = 0; n < 4; n++)
#pragma unroll
            for (int j = 0; j < 4; j++) {
                int row = bm * 128 + wm * 64 + m * 16 + 4 * g + j;
                int col = bn * 128 + wn * 64 + n * 16 + c0;
                C[(size_t)row * 3072 + col] = f2bf(acc[m][n][j]);
            }
}

// ---------- V -> plain V^T: Vtp[bh][d][s] (no permutation; 32x32 B-frags are key-contiguous) ----------
__global__ __launch_bounds__(256) void transpose_v(const u16* __restrict__ QKV, u16* __restrict__ Vtp) {
    __shared__ u16 tile[64][72];
    const int bh = blockIdx.x >> 5, st = blockIdx.x & 31;
    const int b = bh >> 4, h = bh & 15;
    const u16* src = QKV + (size_t)b * S_LEN * 3072 + 2048 + h * 64;
    const int sl = threadIdx.x >> 2;
    const int cg = (threadIdx.x & 3) * 16;
#pragma unroll
    for (int ii = 0; ii < 2; ii++) {
        u16x8 v = *(const u16x8*)(src + (size_t)(st * 64 + sl) * 3072 + cg + ii * 8);
        *(u16x8*)&tile[sl][cg + ii * 8] = v;
    }
    __syncthreads();
    const int dl = threadIdx.x >> 2;
#pragma unroll
    for (int ii = 0; ii < 2; ii++) {
        u16x8 o;
#pragma unroll
        for (int q = 0; q < 8; q++) {
            int p = cg + ii * 8 + q;
            o[q] = tile[p][dl];
        }
        *(u16x8*)(Vtp + ((size_t)bh * 64 + dl) * S_LEN + st * 64 + cg + ii * 8) = o;
    }
}

// ---------- Flash attention v8: 32x32x16 MFMA, 32 q-rows/wave, 4 waves/block (128q),
// swapped QK^T (C[key][q]), P half-exchange via shfl_xor(32), l via ones-MFMA. ----------
// A-frag (32x32x16): lane l holds A[row=l&31][k=8*(l>>5)+j]; B: B[k=8*(l>>5)+j][col=l&31].
// C/D: col=lane&31, row=(reg&3)+8*(reg>>2)+4*(lane>>5)  [guide-verified m74/m101].
__global__ __launch_bounds__(256, 2) void attn8(const u16* __restrict__ QKV, const u16* __restrict__ Vtp,
                                                float* __restrict__ outp) {
    __shared__ alignas(16) u16 Ks[2][64 * 64];   // [key][d-chunk], chunk^=(key&7)
    __shared__ alignas(16) u16 Vs[2][64 * 64];   // [d][pos-chunk], chunk^=(d&7)
    const int bid = blockIdx.x;
    const int wg = ((bid & 7) << 6) | (bid >> 3);   // 512 = 8*64, bijective XCD swizzle
    const int tid = threadIdx.x, l = tid & 63, w = tid >> 6;
    const int qt = wg & 15, bh = wg >> 4;           // 16 q-tiles x 32 bh
    const int b = bh >> 4, h = bh & 15;
    const int l5 = l & 31, hi = l >> 5;
    const u16* Qb = QKV + (size_t)b * S_LEN * 3072 + h * 64;
    const u16* Kb = Qb + 1024;
    const u16* Vb = Vtp + (size_t)bh * 64 * S_LEN;
    const int qbase = qt * 128 + w * 32;

    // staging: chunks i0=tid, i1=tid+256 (rows 0-31 / 32-63), pre-swizzled source col
    const int r0 = tid >> 3, cs0 = (tid & 7) ^ (r0 & 7);
    const int i1 = tid + 256, r1 = i1 >> 3, cs1 = (i1 & 7) ^ (r1 & 7);
    const int dbA = (w * 64) * 8, dbB = (256 + w * 64) * 8;

    // LDS read byte-offsets: off[x][ks] serves K (x=kb) and V (x=d0-tile):
    // row = x*32 + l5, want global chunk (2ks+hi) -> linear chunk (2ks+hi)^(row&7)
    int off[2][4];
#pragma unroll
    for (int x = 0; x < 2; x++)
#pragma unroll
        for (int ks = 0; ks < 4; ks++)
            off[x][ks] = (x * 32 + l5) * 128 + (((2 * ks + hi) ^ (l5 & 7)) << 4);

    // Q B-frags: qf[ks][j] = Q[qbase+l5][16ks + 8hi + j] * scale
    bf16x8 qf[4];
    {
        const float qs = 0.125f * 1.44269504f;
#pragma unroll
        for (int ks = 0; ks < 4; ks++) {
            u16x8 v = *(const u16x8*)(Qb + (size_t)(qbase + l5) * 3072 + ks * 16 + hi * 8);
            bf16x8 q;
#pragma unroll
            for (int j = 0; j < 8; j++) q[j] = (__bf16)(bf2f(v[j]) * qs);
            qf[ks] = q;
        }
    }
    bf16x8 vone;
#pragma unroll
    for (int j = 0; j < 8; j++) vone[j] = (__bf16)1.0f;

    float m_r = -INFINITY;
    f32x16 accO0 = {}, accO1 = {}, accL = {};

    // prologue: stage tile 0 into buf 0
    gload16(Kb + (size_t)r0 * 3072 + cs0 * 8, Ks[0] + dbA);
    gload16(Kb + (size_t)r1 * 3072 + cs1 * 8, Ks[0] + dbB);
    gload16(Vb + (size_t)r0 * S_LEN + cs0 * 8, Vs[0] + dbA);
    gload16(Vb + (size_t)r1 * S_LEN + cs1 * 8, Vs[0] + dbB);

    for (int t = 0; t < 32; t++) {
        const int cur = t & 1;
        __syncthreads();
        if (t + 1 < 32) {
            const int kvn = (t + 1) * 64;
            gload16(Kb + (size_t)(kvn + r0) * 3072 + cs0 * 8, Ks[cur ^ 1] + dbA);
            gload16(Kb + (size_t)(kvn + r1) * 3072 + cs1 * 8, Ks[cur ^ 1] + dbB);
            gload16(Vb + (size_t)r0 * S_LEN + kvn + cs0 * 8, Vs[cur ^ 1] + dbA);
            gload16(Vb + (size_t)r1 * S_LEN + kvn + cs1 * 8, Vs[cur ^ 1] + dbB);
        }
        const char* Kc = (const char*)Ks[cur];
        const char* Vc = (const char*)Vs[cur];
        // QK^T swapped: sck[kb] = C[key=32kb+crow][q=l5]
        f32x16 sck0 = {}, sck1 = {};
        __builtin_amdgcn_s_setprio(1);
#pragma unroll
        for (int ks = 0; ks < 4; ks++) {
            bf16x8 kf0 = *(const bf16x8*)(Kc + off[0][ks]);
            bf16x8 kf1 = *(const bf16x8*)(Kc + off[1][ks]);
            sck0 = __builtin_amdgcn_mfma_f32_32x32x16_bf16(kf0, qf[ks], sck0, 0, 0, 0);
            sck1 = __builtin_amdgcn_mfma_f32_32x32x16_bf16(kf1, qf[ks], sck1, 0, 0, 0);
        }
        __builtin_amdgcn_s_setprio(0);
        // row max over this lane's 32 values (q = l5), then merge with partner half
        float mx;
        {
            float a0 = fmaxf(fmaxf(sck0[0], sck0[1]), sck0[2]);
            float a1 = fmaxf(fmaxf(sck0[3], sck0[4]), sck0[5]);
            float a2 = fmaxf(fmaxf(sck0[6], sck0[7]), sck0[8]);
            float a3 = fmaxf(fmaxf(sck0[9], sck0[10]), sck0[11]);
            float a4 = fmaxf(fmaxf(sck0[12], sck0[13]), sck0[14]);
            float a5 = fmaxf(fmaxf(sck0[15], sck1[0]), sck1[1]);
            float a6 = fmaxf(fmaxf(sck1[2], sck1[3]), sck1[4]);
            float a7 = fmaxf(fmaxf(sck1[5], sck1[6]), sck1[7]);
            float a8 = fmaxf(fmaxf(sck1[8], sck1[9]), sck1[10]);
            float a9 = fmaxf(fmaxf(sck1[11], sck1[12]), sck1[13]);
            float aa = fmaxf(sck1[14], sck1[15]);
            mx = fmaxf(fmaxf(fmaxf(fmaxf(a0, a1), fmaxf(a2, a3)), fmaxf(fmaxf(a4, a5), fmaxf(a6, a7))),
                       fmaxf(fmaxf(a8, a9), aa));
        }
        mx = fmaxf(mx, __shfl_xor(mx, 32));
        // defer-max (T13)
        if (!__all(mx <= m_r + 8.f)) {
            float mnew = fmaxf(m_r, mx);
            float alpha = __builtin_amdgcn_exp2f(m_r - mnew);
            m_r = mnew;
#pragma unroll
            for (int r = 0; r < 16; r++) {
                int cr = (r & 3) + 8 * (r >> 2) + 4 * hi;   // q-row of acc reg r
                float ar = __shfl(alpha, cr);
                accL[r] *= ar; accO0[r] *= ar; accO1[r] *= ar;
            }
        }
        // exp2 (P values, q = l5)
#pragma unroll
        for (int r = 0; r < 16; r++) {
            sck0[r] = __builtin_amdgcn_exp2f(sck0[r] - m_r);
            sck1[r] = __builtin_amdgcn_exp2f(sck1[r] - m_r);
        }
        // pack to bf16 pairs: group u (u=0..3) of kb covers keys' 4hi+8u+{0..3}
        // gA = even groups (u=2t2), gB = odd (u=2t2+1); E = what partner needs = hi? gA : gB
        unsigned int gA[2][2][2], gB[2][2][2], rcvE[2][2][2];
#pragma unroll
        for (int kb = 0; kb < 2; kb++) {
            const f32x16& s = kb ? sck1 : sck0;
#pragma unroll
            for (int t2 = 0; t2 < 2; t2++) {
                int ue = 8 * t2, uo = 8 * t2 + 4;           // reg base of group u=2t2, u=2t2+1
                gA[kb][t2][0] = pk2(s[ue + 0], s[ue + 1]);
                gA[kb][t2][1] = pk2(s[ue + 2], s[ue + 3]);
                gB[kb][t2][0] = pk2(s[uo + 0], s[uo + 1]);
                gB[kb][t2][1] = pk2(s[uo + 2], s[uo + 3]);
#pragma unroll
                for (int p = 0; p < 2; p++) {
                    unsigned int E = hi ? gA[kb][t2][p] : gB[kb][t2][p];
                    rcvE[kb][t2][p] = __shfl_xor((int)E, 32);
                }
            }
        }
        // PV + l: pf[ks] A-frag, kb=ks>>1, t2=ks&1
        __builtin_amdgcn_s_setprio(1);
#pragma unroll
        for (int ks = 0; ks < 4; ks++) {
            const int kb = ks >> 1, t2 = ks & 1;
            u32x4 pu;
            pu[0] = hi ? rcvE[kb][t2][0] : gA[kb][t2][0];
            pu[1] = hi ? rcvE[kb][t2][1] : gA[kb][t2][1];
            pu[2] = hi ? gB[kb][t2][0] : rcvE[kb][t2][0];
            pu[3] = hi ? gB[kb][t2][1] : rcvE[kb][t2][1];
            bf16x8 pf = __builtin_bit_cast(bf16x8, pu);
            bf16x8 vf0 = *(const bf16x8*)(Vc + off[0][ks]);
            bf16x8 vf1 = *(const bf16x8*)(Vc + off[1][ks]);
            accL = __builtin_amdgcn_mfma_f32_32x32x16_bf16(pf, vone, accL, 0, 0, 0);
            accO0 = __builtin_amdgcn_mfma_f32_32x32x16_bf16(pf, vf0, accO0, 0, 0, 0);
            accO1 = __builtin_amdgcn_mfma_f32_32x32x16_bf16(pf, vf1, accO1, 0, 0, 0);
        }
        __builtin_amdgcn_s_setprio(0);
    }
    // epilogue: acc reg r -> q = qbase + crow(r), cols d = d0*32 + l5; accL[r] = row-sum
#pragma unroll
    for (int r = 0; r < 16; r++) {
        int cr = (r & 3) + 8 * (r >> 2) + 4 * hi;
        float inv = 1.0f / accL[r];
        float* op = outp + ((size_t)b * S_LEN + qbase + cr) * DMODEL + h * 64;
        op[l5] = accO0[r] * inv;
        op[32 + l5] = accO1[r] * inv;
    }
}

extern "C" void kernel_launch(void* const* d_in, const int* in_sizes, int n_in,
                              void* d_out, int out_size, void* d_ws, size_t ws_size,
                              hipStream_t stream) {
    const float* X = (const float*)d_in[0];
    const float* W = (const float*)d_in[1];
    float* out = (float*)d_out;

    u16* Xb  = (u16*)d_ws;                        // 4096*1024 bf16
    u16* Wt  = Xb + (size_t)4096 * 1024;          // 3072*1024 bf16
    u16* QKV = Wt + (size_t)3072 * 1024;          // 4096*3072 bf16
    u16* Vtp = QKV + (size_t)4096 * 3072;         // 32*64*2048 bf16 (~48MB total)

    cvt_x<<<4096, 256, 0, stream>>>(X, Xb);
    transpose_w<<<dim3(96, 32), 256, 0, stream>>>(W, Wt);
    qkv_gemm<<<dim3(24, 32), 256, 0, stream>>>(Xb, Wt, QKV);
    transpose_v<<<1024, 256, 0, stream>>>(QKV, Vtp);
    attn8<<<512, 256, 0, stream>>>(QKV, Vtp, out);
}